// Round 2
// baseline (228.498 us; speedup 1.0000x reference)
//
#include <hip/hip_runtime.h>

#define BB 4
#define PP 8
#define NN 4096
#define EE 65536
#define CC 64

// ---------------- workspace layout (bytes) ----------------
// h     : [B][P][N][C] f32  @ 0          (33,554,432)
// deg   : [B][N] int        @ 33554432   (65,536)
// cursor: [B][N] int        @ 33619968   (65,536)   <- deg+cursor zeroed by one memset
// offs  : [B][N+1] int      @ 33685504   (65,552)
// dinv  : [B][N] f32        @ 33751056   (65,536)
// bsrc  : [B][E] int        @ 33816592   (1,048,576)
// bw    : [B][E] f32        @ 34865168   (1,048,576)
// total ~ 35.9 MB

#define OFF_DEG   33554432u
#define OFF_CUR   33619968u
#define OFF_OFFS  33685504u
#define OFF_DINV  33751056u
#define OFF_BSRC  33816592u
#define OFF_BW    34865168u

// ---------------- GEMM: h[row][c] = sum_k x[row][k] * W[k][c] ----------------
// rows = B*P*N = 131072, flat row-major (same layout as x), K = C = 64.
// W column held in 64 VGPRs per thread; x rows staged 1 KB at a time in LDS.
__global__ __launch_bounds__(256) void k_gemm(const float* __restrict__ x,
                                              const float* __restrict__ W,
                                              float* __restrict__ h) {
    __shared__ __align__(16) float xl[256];
    const int lane = threadIdx.x & 63;
    const int wv   = threadIdx.x >> 6;

    float wreg[64];
#pragma unroll
    for (int k = 0; k < 64; ++k) wreg[k] = W[k * 64 + lane];

    const int rows_per_blk = (BB * PP * NN) / 1024;  // 128
    const int rbase0 = blockIdx.x * rows_per_blk;

    for (int it = 0; it < rows_per_blk; it += 4) {
        const int rbase = rbase0 + it;
        __syncthreads();
        xl[threadIdx.x] = x[(size_t)rbase * 64 + threadIdx.x];
        __syncthreads();
        const float4* xl4 = (const float4*)&xl[wv * 64];
        float acc = 0.f;
#pragma unroll
        for (int k4 = 0; k4 < 16; ++k4) {
            float4 xv = xl4[k4];
            acc = fmaf(xv.x, wreg[4 * k4 + 0], acc);
            acc = fmaf(xv.y, wreg[4 * k4 + 1], acc);
            acc = fmaf(xv.z, wreg[4 * k4 + 2], acc);
            acc = fmaf(xv.w, wreg[4 * k4 + 3], acc);
        }
        h[(size_t)(rbase + wv) * 64 + lane] = acc;
    }
}

// ---------------- degree histogram over dst ----------------
__global__ void k_hist(const int* __restrict__ ei, int* __restrict__ cnt) {
    const int idx = blockIdx.x * blockDim.x + threadIdx.x;  // 0 .. B*E
    const int b = idx >> 16;         // E = 65536
    const int e = idx & (EE - 1);
    const int d = ei[(size_t)b * 2 * EE + EE + e];
    atomicAdd(&cnt[b * NN + d], 1);
}

// ---------------- per-batch exclusive scan + dinv ----------------
__global__ __launch_bounds__(1024) void k_scan(const int* __restrict__ cnt,
                                               int* __restrict__ offs,
                                               float* __restrict__ dinv) {
    __shared__ int sums[1024];
    const int b = blockIdx.x, t = threadIdx.x;
    int v[4];
    int s = 0;
#pragma unroll
    for (int j = 0; j < 4; ++j) { v[j] = cnt[b * NN + t * 4 + j]; s += v[j]; }
    sums[t] = s;
    __syncthreads();
    for (int off = 1; off < 1024; off <<= 1) {
        const int add = (t >= off) ? sums[t - off] : 0;
        __syncthreads();
        sums[t] += add;
        __syncthreads();
    }
    int run = sums[t] - s;  // exclusive prefix of this thread's 4 elements
#pragma unroll
    for (int j = 0; j < 4; ++j) {
        const int i = t * 4 + j;
        offs[b * (NN + 1) + i] = run;
        dinv[b * NN + i] = rsqrtf((float)(v[j] + 1));  // +1 = self loop
        run += v[j];
    }
    if (t == 1023) offs[b * (NN + 1) + NN] = run;  // == E
}

// ---------------- CSR bucket fill: (src, dinv[src]) per dst-slot ----------------
__global__ void k_bucket(const int* __restrict__ ei, const int* __restrict__ offs,
                         const float* __restrict__ dinv, int* __restrict__ cursor,
                         int* __restrict__ bsrc, float* __restrict__ bw) {
    const int idx = blockIdx.x * blockDim.x + threadIdx.x;
    const int b = idx >> 16;
    const int e = idx & (EE - 1);
    const int s = ei[(size_t)b * 2 * EE + e];
    const int d = ei[(size_t)b * 2 * EE + EE + e];
    const int pos = atomicAdd(&cursor[b * NN + d], 1);
    const int slot = offs[b * (NN + 1) + d] + pos;
    bsrc[(size_t)b * EE + slot] = s;
    bw[(size_t)b * EE + slot] = dinv[b * NN + s];
}

// ---------------- aggregation + bias + PReLU, frame-local ----------------
// One WAVE per (b, p, node i); lane = channel c. Blocks are (b,p)-major so the
// machine sweeps one 1 MB h-frame at a time -> gather stays L2-resident.
// acc = dinv[i]*h[i] + sum_e dinv[src]*h[src]; out = prelu(dinv[i]*acc + bias).
__global__ __launch_bounds__(256) void k_agg(const float* __restrict__ h,
                                             const int* __restrict__ offs,
                                             const float* __restrict__ dinv,
                                             const int* __restrict__ bsrc,
                                             const float* __restrict__ bw,
                                             const float* __restrict__ bias,
                                             const float* __restrict__ pa,
                                             float* __restrict__ out) {
    const int lane = threadIdx.x & 63;
    const int wv   = threadIdx.x >> 6;
    const int g    = blockIdx.x;            // 32768 blocks, (b,p)-major
    const int bp   = g >> 10;               // 0..31
    const int b    = bp >> 3;
    const int i    = ((g & 1023) << 2) + wv;  // node 0..4095

    const float* hb  = h + (size_t)bp * NN * 64;  // h[b][p][.][.]
    const int*   bs  = bsrc + (size_t)b * EE;
    const float* bww = bw + (size_t)b * EE;

    const int start = offs[b * (NN + 1) + i];
    const int end   = offs[b * (NN + 1) + i + 1];
    const float di  = dinv[b * NN + i];

    float a0 = di * hb[(size_t)i * 64 + lane];  // self loop
    float a1 = 0.f, a2 = 0.f, a3 = 0.f;

    int e = start;
    for (; e + 4 <= end; e += 4) {
        const int j0 = bs[e], j1 = bs[e + 1], j2 = bs[e + 2], j3 = bs[e + 3];
        const float w0 = bww[e], w1 = bww[e + 1], w2 = bww[e + 2], w3 = bww[e + 3];
        a0 = fmaf(w0, hb[(size_t)j0 * 64 + lane], a0);
        a1 = fmaf(w1, hb[(size_t)j1 * 64 + lane], a1);
        a2 = fmaf(w2, hb[(size_t)j2 * 64 + lane], a2);
        a3 = fmaf(w3, hb[(size_t)j3 * 64 + lane], a3);
    }
    for (; e < end; ++e)
        a0 = fmaf(bww[e], hb[(size_t)bs[e] * 64 + lane], a0);

    const float acc = (a0 + a1) + (a2 + a3);
    float r = fmaf(di, acc, bias[lane]);
    const float a = pa[0];
    r = r >= 0.f ? r : a * r;
    out[((size_t)bp * NN + i) * 64 + lane] = r;
}

extern "C" void kernel_launch(void* const* d_in, const int* in_sizes, int n_in,
                              void* d_out, int out_size, void* d_ws, size_t ws_size,
                              hipStream_t stream) {
    const float* x    = (const float*)d_in[0];
    const int*   ei   = (const int*)d_in[1];
    const float* W    = (const float*)d_in[2];
    const float* bias = (const float*)d_in[3];
    const float* pa   = (const float*)d_in[4];
    float* out = (float*)d_out;

    char* ws = (char*)d_ws;
    float* h    = (float*)ws;
    int*   deg  = (int*)(ws + OFF_DEG);
    int*   cur  = (int*)(ws + OFF_CUR);
    int*   offs = (int*)(ws + OFF_OFFS);
    float* dinv = (float*)(ws + OFF_DINV);
    int*   bsrc = (int*)(ws + OFF_BSRC);
    float* bw   = (float*)(ws + OFF_BW);

    // zero deg + cursor (contiguous 128 KB); ws is re-poisoned before every call
    hipMemsetAsync(deg, 0, 2 * BB * NN * sizeof(int), stream);

    k_gemm<<<1024, 256, 0, stream>>>(x, W, h);
    k_hist<<<(BB * EE) / 256, 256, 0, stream>>>(ei, deg);
    k_scan<<<BB, 1024, 0, stream>>>(deg, offs, dinv);
    k_bucket<<<(BB * EE) / 256, 256, 0, stream>>>(ei, offs, dinv, cur, bsrc, bw);
    k_agg<<<(BB * PP * NN) / 4, 256, 0, stream>>>(h, offs, dinv, bsrc, bw, bias, pa, out);
}